// Round 3
// baseline (5867.733 us; speedup 1.0000x reference)
//
#include <hip/hip_runtime.h>

#define B_ 4
#define N_ 16384
#define D_ 125
#define S_ 2048
#define K_ 16
#define C0_ 128
#define C1_ 128
#define C2_ 256
#define NSLOT 64

typedef float v2f __attribute__((ext_vector_type(2)));

// ---------------------------------------------------------------------------
// FPS: one block per batch, 512 threads (2 waves/SIMD), 32 points/thread in
// registers (launch_bounds(512,2) -> 256 VGPR budget so arrays stay resident).
// Hot loop is value-only (packed dist+min+max); argmax index recovered by a
// bitwise-equality rescan with min-index tie-break. Centroid outputs are
// captured in registers and flushed once per 512-iteration epoch.
// Bit-exact vs numpy: contract(off) keeps mul/mul/add/add rounding, fminf,
// argmax with first-index tie-break at every level.
// ---------------------------------------------------------------------------
__global__ __launch_bounds__(512, 2) void fps_kernel(const float* __restrict__ xyz,
                                                     float* __restrict__ new_xyz) {
#pragma clang fp contract(off)
  const int b = blockIdx.x;
  const float* X = xyz + (size_t)b * N_ * 3;
  const int t = threadIdx.x;
  constexpr int PAIRS = N_ / 512 / 2;  // 16 pairs = 32 points/thread
  v2f px[PAIRS], py[PAIRS], pz[PAIRS], d[PAIRS];
  const int base = t * (2 * PAIRS);
#pragma unroll
  for (int j = 0; j < PAIRS; ++j) {
    const int i0 = (base + 2 * j) * 3;
    px[j] = (v2f){X[i0 + 0], X[i0 + 3]};
    py[j] = (v2f){X[i0 + 1], X[i0 + 4]};
    pz[j] = (v2f){X[i0 + 2], X[i0 + 5]};
    d[j] = (v2f){1e10f, 1e10f};
  }
  __shared__ float s_val[2][8];
  __shared__ int s_idx[2][8];
  float cx = X[0], cy = X[1], cz = X[2];  // centroid 0 (broadcast load, once)
  float cap_x = 0.f, cap_y = 0.f, cap_z = 0.f;  // per-thread output capture
  for (int s = 0; s < S_; ++s) {
    if (((s - t) & 511) == 0) { cap_x = cx; cap_y = cy; cap_z = cz; }  // s%512==t
    if ((s & 511) == 511) {  // epoch flush: 512 coalesced centroids
      const int o = ((size_t)0, (b * S_ + (s & ~511) + t) * 3);
      new_xyz[o + 0] = cap_x;
      new_xyz[o + 1] = cap_y;
      new_xyz[o + 2] = cap_z;
    }
    if (s == S_ - 1) break;  // last index needs no further update
    const v2f c2x = {cx, cx}, c2y = {cy, cy}, c2z = {cz, cz};
    // ---- phase 1: value-only update (packed) ----
    v2f m2 = {-1.0f, -1.0f};
#pragma unroll
    for (int j = 0; j < PAIRS; ++j) {
      v2f dx = px[j] - c2x;
      v2f dy = py[j] - c2y;
      v2f dz = pz[j] - c2z;
      v2f sq = (dx * dx + dy * dy) + dz * dz;  // contract(off): exact ref order
      v2f dm;
      dm.x = fminf(d[j].x, sq.x);
      dm.y = fminf(d[j].y, sq.y);
      d[j] = dm;
      m2.x = fmaxf(m2.x, dm.x);
      m2.y = fmaxf(m2.y, dm.y);
    }
    float lmax = fmaxf(m2.x, m2.y);
    // ---- phase 2: recover first (smallest) index attaining lmax ----
    int lidx = 0x7fffffff;
#pragma unroll
    for (int j = 0; j < PAIRS; ++j) {
      if (d[j].x == lmax) lidx = min(lidx, base + 2 * j);
      if (d[j].y == lmax) lidx = min(lidx, base + 2 * j + 1);
    }
    // ---- wave argmax (tie -> smaller index) ----
#pragma unroll
    for (int off = 32; off > 0; off >>= 1) {
      float ov = __shfl_down(lmax, off);
      int oi = __shfl_down(lidx, off);
      if (ov > lmax || (ov == lmax && oi < lidx)) { lmax = ov; lidx = oi; }
    }
    const int buf = s & 1;
    if ((t & 63) == 0) { s_val[buf][t >> 6] = lmax; s_idx[buf][t >> 6] = lidx; }
    __syncthreads();
    // all threads redundantly scan the 8 partials (broadcast LDS reads)
    float bv = s_val[buf][0];
    int bi = s_idx[buf][0];
#pragma unroll
    for (int w = 1; w < 8; ++w) {
      float v = s_val[buf][w];
      int i = s_idx[buf][w];
      if (v > bv || (v == bv && i < bi)) { bv = v; bi = i; }
    }
    // centroid for next iter (same address across lanes -> broadcast, L2-hot)
    cx = X[bi * 3 + 0];
    cy = X[bi * 3 + 1];
    cz = X[bi * 3 + 2];
  }
}

// ---------------------------------------------------------------------------
// kNN: one block (256 thr) per query. Distances in LDS; 16 rounds of
// block-min with winner-only local rescan. Set semantics (order irrelevant).
// ---------------------------------------------------------------------------
__global__ __launch_bounds__(256) void knn_kernel(const float* __restrict__ xyz,
                                                  const float* __restrict__ new_xyz,
                                                  int* __restrict__ knn_idx) {
  const int q = blockIdx.x;  // b*S + s
  const int b = q / S_;
  __shared__ float sd[N_];  // 64 KB
  __shared__ float s_minv[4];
  __shared__ int s_mini[4];
  __shared__ int s_win;
  const int t = threadIdx.x;
  const float qx = new_xyz[q * 3 + 0];
  const float qy = new_xyz[q * 3 + 1];
  const float qz = new_xyz[q * 3 + 2];
  const float* X = xyz + (size_t)b * N_ * 3;
  float lmin = 1e30f;
  int lidx = -1;
  for (int j = 0; j < N_ / 256; ++j) {
    int i = t + j * 256;
    float dx = X[i * 3 + 0] - qx;
    float dy = X[i * 3 + 1] - qy;
    float dz = X[i * 3 + 2] - qz;
    float dsq = fmaf(dx, dx, fmaf(dy, dy, dz * dz));
    sd[i] = dsq;
    if (dsq < lmin) { lmin = dsq; lidx = i; }
  }
  __syncthreads();
  for (int r = 0; r < K_; ++r) {
    float v = lmin;
    int ii = lidx;
#pragma unroll
    for (int off = 32; off > 0; off >>= 1) {
      float ov = __shfl_down(v, off);
      int oi = __shfl_down(ii, off);
      if (ov < v) { v = ov; ii = oi; }
    }
    if ((t & 63) == 0) { s_minv[t >> 6] = v; s_mini[t >> 6] = ii; }
    __syncthreads();
    if (t == 0) {
      float bv = s_minv[0]; int bi = s_mini[0];
#pragma unroll
      for (int w = 1; w < 4; ++w)
        if (s_minv[w] < bv) { bv = s_minv[w]; bi = s_mini[w]; }
      knn_idx[q * K_ + r] = bi;
      s_win = bi;
    }
    __syncthreads();
    int wi = s_win;
    if (wi == lidx) {  // unique owner (disjoint index ranges per thread)
      sd[wi] = 1e30f;
      lmin = 1e30f; lidx = -1;
      for (int j = 0; j < N_ / 256; ++j) {
        int i = t + j * 256;
        float dv = sd[i];
        if (dv < lmin) { lmin = dv; lidx = i; }
      }
    }
  }
}

// ---------------------------------------------------------------------------
// Transpose weights into ws (coalesced per-channel access later) and zero the
// stats region (exactly 49152 elements == transpose work, handled same grid).
// ---------------------------------------------------------------------------
__global__ __launch_bounds__(256) void prep_kernel(const float* __restrict__ W1,
                                                   const float* __restrict__ W2,
                                                   float* __restrict__ W1t,
                                                   float* __restrict__ W2t,
                                                   float* __restrict__ stats) {
  int e = blockIdx.x * 256 + threadIdx.x;  // 0 .. 49151
  stats[e] = 0.0f;
  if (e < C1_ * C0_) {
    int co = e / C0_, c = e % C0_;
    W1t[c * C1_ + co] = W1[e];
  } else {
    int e2 = e - C1_ * C0_;
    int co = e2 / C1_, c = e2 % C1_;
    W2t[c * C2_ + co] = W2[e2];
  }
}

// ---------------------------------------------------------------------------
// conv1 stats: gather + conv1 (y1 pre-BN), accumulate per-channel sum/sumsq.
// Grid 1024 blocks x 8 queries each; slot-sliced atomics (64 slots).
// ---------------------------------------------------------------------------
__global__ __launch_bounds__(256) void conv1_stats_kernel(
    const float* __restrict__ xyz, const float* __restrict__ feat,
    const float* __restrict__ new_xyz, const int* __restrict__ knn,
    const float* __restrict__ W1t, const float* __restrict__ b1,
    float* __restrict__ stats1) {
  __shared__ __align__(16) float sinT[C0_][K_];  // transposed: [c][k]
  __shared__ int sidx[K_];
  __shared__ float sred[256];
  const int t = threadIdx.x;
  float psum = 0.f, psumsq = 0.f;
  const int QPB = (B_ * S_) / 1024;  // 8
  for (int qq = 0; qq < QPB; ++qq) {
    const int q = blockIdx.x * QPB + qq;
    const int b = q / S_;
    if (t < K_) sidx[t] = knn[q * K_ + t];
    __syncthreads();
    const float nx = new_xyz[q * 3 + 0];
    const float ny = new_xyz[q * 3 + 1];
    const float nz = new_xyz[q * 3 + 2];
    for (int e = t; e < K_ * C0_; e += 256) {
      int c = e >> 4, kk = e & 15;
      int i = sidx[kk];
      float v;
      if (c < 3)
        v = xyz[((size_t)b * N_ + i) * 3 + c] - (c == 0 ? nx : (c == 1 ? ny : nz));
      else
        v = feat[((size_t)b * N_ + i) * D_ + (c - 3)];
      sinT[c][kk] = v;
    }
    __syncthreads();
    const int co = t & 127, kh = t >> 7;
    float acc[8];
    float bias = b1[co];
#pragma unroll
    for (int k = 0; k < 8; ++k) acc[k] = bias;
    for (int c = 0; c < C0_; ++c) {
      float w = W1t[c * C1_ + co];
      float4 xa = *(const float4*)&sinT[c][kh * 8];
      float4 xb = *(const float4*)&sinT[c][kh * 8 + 4];
      acc[0] = fmaf(w, xa.x, acc[0]);
      acc[1] = fmaf(w, xa.y, acc[1]);
      acc[2] = fmaf(w, xa.z, acc[2]);
      acc[3] = fmaf(w, xa.w, acc[3]);
      acc[4] = fmaf(w, xb.x, acc[4]);
      acc[5] = fmaf(w, xb.y, acc[5]);
      acc[6] = fmaf(w, xb.z, acc[6]);
      acc[7] = fmaf(w, xb.w, acc[7]);
    }
#pragma unroll
    for (int k = 0; k < 8; ++k) {
      psum += acc[k];
      psumsq = fmaf(acc[k], acc[k], psumsq);
    }
    __syncthreads();
  }
  sred[t] = psum;
  __syncthreads();
  float totsum = (t < 128) ? (sred[t] + sred[t + 128]) : 0.f;
  __syncthreads();
  sred[t] = psumsq;
  __syncthreads();
  if (t < 128) {
    float totsq = sred[t] + sred[t + 128];
    float* st = stats1 + (size_t)(blockIdx.x & (NSLOT - 1)) * (2 * C1_);
    atomicAdd(&st[t], totsum);
    atomicAdd(&st[C1_ + t], totsq);
  }
}

__global__ void finalize1_kernel(const float* __restrict__ stats1,
                                 const float* __restrict__ gamma1,
                                 const float* __restrict__ beta1,
                                 float* __restrict__ ss1) {
  int t = threadIdx.x;  // 128
  float s = 0.f, sq = 0.f;
  for (int w = 0; w < NSLOT; ++w) {
    s += stats1[w * 2 * C1_ + t];
    sq += stats1[w * 2 * C1_ + C1_ + t];
  }
  const float M = (float)(B_ * S_ * K_);
  float m = s / M;
  float v = fmaxf(sq / M - m * m, 0.f);
  float sc = gamma1[t] * rsqrtf(v + 1e-5f);
  ss1[t] = sc;
  ss1[C1_ + t] = fmaf(-m, sc, beta1[t]);
}

// ---------------------------------------------------------------------------
// conv2: re-gather, recompute conv1, apply bn1+relu -> LDS, conv2, per-(q,co2)
// max/min over k, accumulate y2 stats. Grid 1024 x 8 queries.
// ---------------------------------------------------------------------------
__global__ __launch_bounds__(256) void conv2_kernel(
    const float* __restrict__ xyz, const float* __restrict__ feat,
    const float* __restrict__ new_xyz, const int* __restrict__ knn,
    const float* __restrict__ W1t, const float* __restrict__ b1,
    const float* __restrict__ ss1, const float* __restrict__ W2t,
    const float* __restrict__ b2, float* __restrict__ maxv,
    float* __restrict__ minv, float* __restrict__ stats2) {
  __shared__ __align__(16) float sinT[C0_][K_];
  __shared__ __align__(16) float sh1T[C1_][20];  // pad 16->20 (bank spread, 16B-aligned rows)
  __shared__ int sidx[K_];
  const int t = threadIdx.x;
  float psum = 0.f, psumsq = 0.f;
  const int QPB = (B_ * S_) / 1024;  // 8
  for (int qq = 0; qq < QPB; ++qq) {
    const int q = blockIdx.x * QPB + qq;
    const int b = q / S_;
    if (t < K_) sidx[t] = knn[q * K_ + t];
    __syncthreads();
    const float nx = new_xyz[q * 3 + 0];
    const float ny = new_xyz[q * 3 + 1];
    const float nz = new_xyz[q * 3 + 2];
    for (int e = t; e < K_ * C0_; e += 256) {
      int c = e >> 4, kk = e & 15;
      int i = sidx[kk];
      float v;
      if (c < 3)
        v = xyz[((size_t)b * N_ + i) * 3 + c] - (c == 0 ? nx : (c == 1 ? ny : nz));
      else
        v = feat[((size_t)b * N_ + i) * D_ + (c - 3)];
      sinT[c][kk] = v;
    }
    __syncthreads();
    {  // conv1 + bn1 + relu -> sh1T[c_in2][k]
      const int co = t & 127, kh = t >> 7;
      float acc[8];
      float bias = b1[co];
#pragma unroll
      for (int k = 0; k < 8; ++k) acc[k] = bias;
      for (int c = 0; c < C0_; ++c) {
        float w = W1t[c * C1_ + co];
        float4 xa = *(const float4*)&sinT[c][kh * 8];
        float4 xb = *(const float4*)&sinT[c][kh * 8 + 4];
        acc[0] = fmaf(w, xa.x, acc[0]);
        acc[1] = fmaf(w, xa.y, acc[1]);
        acc[2] = fmaf(w, xa.z, acc[2]);
        acc[3] = fmaf(w, xa.w, acc[3]);
        acc[4] = fmaf(w, xb.x, acc[4]);
        acc[5] = fmaf(w, xb.y, acc[5]);
        acc[6] = fmaf(w, xb.z, acc[6]);
        acc[7] = fmaf(w, xb.w, acc[7]);
      }
      float sc = ss1[co], sh = ss1[C1_ + co];
#pragma unroll
      for (int k = 0; k < 8; ++k) {
        float h = fmaxf(fmaf(acc[k], sc, sh), 0.f);
        sh1T[co][kh * 8 + k] = h;
      }
    }
    __syncthreads();
    {  // conv2: thread t -> co2 = t
      float acc2[16];
      float bias2 = b2[t];
#pragma unroll
      for (int k = 0; k < 16; ++k) acc2[k] = bias2;
      for (int c = 0; c < C1_; ++c) {
        float w = W2t[c * C2_ + t];
        float4 h0 = *(const float4*)&sh1T[c][0];
        float4 h1 = *(const float4*)&sh1T[c][4];
        float4 h2 = *(const float4*)&sh1T[c][8];
        float4 h3 = *(const float4*)&sh1T[c][12];
        acc2[0] = fmaf(w, h0.x, acc2[0]);
        acc2[1] = fmaf(w, h0.y, acc2[1]);
        acc2[2] = fmaf(w, h0.z, acc2[2]);
        acc2[3] = fmaf(w, h0.w, acc2[3]);
        acc2[4] = fmaf(w, h1.x, acc2[4]);
        acc2[5] = fmaf(w, h1.y, acc2[5]);
        acc2[6] = fmaf(w, h1.z, acc2[6]);
        acc2[7] = fmaf(w, h1.w, acc2[7]);
        acc2[8] = fmaf(w, h2.x, acc2[8]);
        acc2[9] = fmaf(w, h2.y, acc2[9]);
        acc2[10] = fmaf(w, h2.z, acc2[10]);
        acc2[11] = fmaf(w, h2.w, acc2[11]);
        acc2[12] = fmaf(w, h3.x, acc2[12]);
        acc2[13] = fmaf(w, h3.y, acc2[13]);
        acc2[14] = fmaf(w, h3.z, acc2[14]);
        acc2[15] = fmaf(w, h3.w, acc2[15]);
      }
      float mx = acc2[0], mn = acc2[0];
#pragma unroll
      for (int k = 0; k < 16; ++k) {
        psum += acc2[k];
        psumsq = fmaf(acc2[k], acc2[k], psumsq);
        mx = fmaxf(mx, acc2[k]);
        mn = fminf(mn, acc2[k]);
      }
      maxv[(size_t)q * C2_ + t] = mx;
      minv[(size_t)q * C2_ + t] = mn;
    }
    __syncthreads();
  }
  float* st = stats2 + (size_t)(blockIdx.x & (NSLOT - 1)) * (2 * C2_);
  atomicAdd(&st[t], psum);
  atomicAdd(&st[C2_ + t], psumsq);
}

__global__ void finalize2_kernel(const float* __restrict__ stats2,
                                 const float* __restrict__ gamma2,
                                 const float* __restrict__ beta2,
                                 float* __restrict__ ss2) {
  int t = threadIdx.x;  // 256
  float s = 0.f, sq = 0.f;
  for (int w = 0; w < NSLOT; ++w) {
    s += stats2[w * 2 * C2_ + t];
    sq += stats2[w * 2 * C2_ + C2_ + t];
  }
  const float M = (float)(B_ * S_ * K_);
  float m = s / M;
  float v = fmaxf(sq / M - m * m, 0.f);
  float sc = gamma2[t] * rsqrtf(v + 1e-5f);
  ss2[t] = sc;
  ss2[C2_ + t] = fmaf(-m, sc, beta2[t]);
}

// max_k relu(bn(y)) == relu(bn(max_k y)) for scale>=0 (min_k for scale<0)
__global__ __launch_bounds__(256) void out_kernel(const float* __restrict__ maxv,
                                                  const float* __restrict__ minv,
                                                  const float* __restrict__ ss2,
                                                  float* __restrict__ out2) {
  int e = blockIdx.x * 256 + threadIdx.x;
  int co = e & (C2_ - 1);
  float sc = ss2[co], sh = ss2[C2_ + co];
  float v = (sc >= 0.f) ? maxv[e] : minv[e];
  out2[e] = fmaxf(fmaf(v, sc, sh), 0.f);
}

extern "C" void kernel_launch(void* const* d_in, const int* in_sizes, int n_in,
                              void* d_out, int out_size, void* d_ws, size_t ws_size,
                              hipStream_t stream) {
  (void)in_sizes; (void)n_in; (void)out_size; (void)ws_size;
  const float* xyz = (const float*)d_in[0];
  const float* feat = (const float*)d_in[1];
  const float* W1 = (const float*)d_in[2];
  const float* b1 = (const float*)d_in[3];
  const float* gamma1 = (const float*)d_in[4];
  const float* beta1 = (const float*)d_in[5];
  const float* W2 = (const float*)d_in[6];
  const float* b2 = (const float*)d_in[7];
  const float* gamma2 = (const float*)d_in[8];
  const float* beta2 = (const float*)d_in[9];

  float* out = (float*)d_out;
  float* new_xyz = out;                 // [B,S,3]
  float* out2 = out + B_ * S_ * 3;      // [B,S,C2]

  float* ws = (float*)d_ws;
  float* stats1 = ws;                              // 64*256
  float* stats2 = stats1 + NSLOT * 2 * C1_;        // 64*512
  float* ss1 = stats2 + NSLOT * 2 * C2_;           // 256
  float* ss2 = ss1 + 2 * C1_;                      // 512
  float* W1t = ss2 + 2 * C2_;                      // 16384
  float* W2t = W1t + C1_ * C0_;                    // 32768
  int* knn = (int*)(W2t + (size_t)C2_ * C1_);      // B*S*K ints
  float* maxv = (float*)(knn + B_ * S_ * K_);      // B*S*C2
  float* minv = maxv + (size_t)B_ * S_ * C2_;      // B*S*C2

  prep_kernel<<<192, 256, 0, stream>>>(W1, W2, W1t, W2t, stats1);
  fps_kernel<<<B_, 512, 0, stream>>>(xyz, new_xyz);
  knn_kernel<<<B_ * S_, 256, 0, stream>>>(xyz, new_xyz, knn);
  conv1_stats_kernel<<<1024, 256, 0, stream>>>(xyz, feat, new_xyz, knn, W1t, b1, stats1);
  finalize1_kernel<<<1, 128, 0, stream>>>(stats1, gamma1, beta1, ss1);
  conv2_kernel<<<1024, 256, 0, stream>>>(xyz, feat, new_xyz, knn, W1t, b1, ss1,
                                         W2t, b2, maxv, minv, stats2);
  finalize2_kernel<<<1, 256, 0, stream>>>(stats2, gamma2, beta2, ss2);
  out_kernel<<<(B_ * S_ * C2_) / 256, 256, 0, stream>>>(maxv, minv, ss2, out2);
}

// Round 4
// 5355.609 us; speedup vs baseline: 1.0956x; 1.0956x over previous
//
#include <hip/hip_runtime.h>

#define B_ 4
#define N_ 16384
#define D_ 125
#define S_ 2048
#define K_ 16
#define C0_ 128
#define C1_ 128
#define C2_ 256
#define NSLOT 64

typedef float v2f __attribute__((ext_vector_type(2)));

// Opaque-ify a float so the compiler cannot rematerialize it from memory.
__device__ __forceinline__ void pin(float& x) { asm volatile("" : "+v"(x)); }

// ---------------------------------------------------------------------------
// FPS: one block per batch, 512 threads (2 waves/SIMD), 32 points/thread in
// registers. Coordinates are pinned via empty inline-asm so the register
// allocator cannot re-load them from global each iteration (round-3 lesson:
// launch_bounds alone does not stop rematerialization; VGPR stayed 84).
// Hot loop: packed dist+min+max (no loads), equality rescan for the index,
// value-only shfl_xor butterfly + ballot/ffs for the wave argmax.
// Bit-exact vs numpy: contract(off) keeps mul/mul/add/add rounding, fminf,
// argmax with first-index tie-break at every level (lowest matching lane =
// smallest point index since per-lane ranges are ordered and disjoint).
// ---------------------------------------------------------------------------
__global__ __launch_bounds__(512, 2) void fps_kernel(const float* __restrict__ xyz,
                                                     float* __restrict__ new_xyz) {
#pragma clang fp contract(off)
  const int b = blockIdx.x;
  const float* X = xyz + (size_t)b * N_ * 3;
  const int t = threadIdx.x;
  constexpr int PAIRS = N_ / 512 / 2;  // 16 pairs = 32 points/thread
  v2f px[PAIRS], py[PAIRS], pz[PAIRS], d[PAIRS];
  const int base = t * (2 * PAIRS);
#pragma unroll
  for (int j = 0; j < PAIRS; ++j) {
    const int i0 = (base + 2 * j) * 3;
    px[j] = (v2f){X[i0 + 0], X[i0 + 3]};
    py[j] = (v2f){X[i0 + 1], X[i0 + 4]};
    pz[j] = (v2f){X[i0 + 2], X[i0 + 5]};
    d[j] = (v2f){1e10f, 1e10f};
  }
  // Pin coordinates into registers (guaranteed-valid scalar round-trip).
#pragma unroll
  for (int j = 0; j < PAIRS; ++j) {
    float a0 = px[j].x, a1 = px[j].y;
    float b0 = py[j].x, b1 = py[j].y;
    float c0 = pz[j].x, c1 = pz[j].y;
    pin(a0); pin(a1); pin(b0); pin(b1); pin(c0); pin(c1);
    px[j] = (v2f){a0, a1};
    py[j] = (v2f){b0, b1};
    pz[j] = (v2f){c0, c1};
  }
  __shared__ float s_val[2][8];
  __shared__ int s_idx[2][8];
  float cx = X[0], cy = X[1], cz = X[2];  // centroid 0 (broadcast load, once)
  float cap_x = 0.f, cap_y = 0.f, cap_z = 0.f;  // per-thread output capture
  for (int s = 0; s < S_; ++s) {
    if (((s - t) & 511) == 0) { cap_x = cx; cap_y = cy; cap_z = cz; }  // s%512==t
    if ((s & 511) == 511) {  // epoch flush: 512 coalesced centroids
      const int o = (b * S_ + (s & ~511) + t) * 3;
      new_xyz[o + 0] = cap_x;
      new_xyz[o + 1] = cap_y;
      new_xyz[o + 2] = cap_z;
    }
    if (s == S_ - 1) break;  // last index needs no further update
    const v2f c2x = {cx, cx}, c2y = {cy, cy}, c2z = {cz, cz};
    // ---- phase 1: value-only update (packed, register-resident) ----
    v2f m2 = {-1.0f, -1.0f};
#pragma unroll
    for (int j = 0; j < PAIRS; ++j) {
      v2f dx = px[j] - c2x;
      v2f dy = py[j] - c2y;
      v2f dz = pz[j] - c2z;
      v2f sq = (dx * dx + dy * dy) + dz * dz;  // contract(off): exact ref order
      v2f dm;
      dm.x = fminf(d[j].x, sq.x);
      dm.y = fminf(d[j].y, sq.y);
      d[j] = dm;
      m2.x = fmaxf(m2.x, dm.x);
      m2.y = fmaxf(m2.y, dm.y);
    }
    const float lmax = fmaxf(m2.x, m2.y);
    // ---- phase 2: recover first (smallest) local index attaining lmax ----
    int lidx = 0x7fffffff;
#pragma unroll
    for (int j = 0; j < PAIRS; ++j) {
      if (d[j].x == lmax) lidx = min(lidx, base + 2 * j);
      if (d[j].y == lmax) lidx = min(lidx, base + 2 * j + 1);
    }
    // ---- wave argmax: value butterfly, then lowest matching lane's index ----
    float wmax = lmax;
#pragma unroll
    for (int off = 32; off > 0; off >>= 1)
      wmax = fmaxf(wmax, __shfl_xor(wmax, off));
    unsigned long long mask = __ballot(lmax == wmax);
    int src = __ffsll(mask) - 1;
    int widx = __shfl(lidx, src);
    const int buf = s & 1;
    if ((t & 63) == 0) { s_val[buf][t >> 6] = wmax; s_idx[buf][t >> 6] = widx; }
    __syncthreads();
    // all threads redundantly scan the 8 partials (broadcast LDS reads)
    float bv = s_val[buf][0];
    int bi = s_idx[buf][0];
#pragma unroll
    for (int w = 1; w < 8; ++w) {
      float v = s_val[buf][w];
      int i = s_idx[buf][w];
      if (v > bv || (v == bv && i < bi)) { bv = v; bi = i; }
    }
    // centroid for next iter (same address across lanes -> broadcast, L2-hot)
    cx = X[bi * 3 + 0];
    cy = X[bi * 3 + 1];
    cz = X[bi * 3 + 2];
  }
}

// ---------------------------------------------------------------------------
// kNN: one block (256 thr) per query. Distances in LDS; 16 rounds of
// block-min with winner-only local rescan. Set semantics (order irrelevant).
// ---------------------------------------------------------------------------
__global__ __launch_bounds__(256) void knn_kernel(const float* __restrict__ xyz,
                                                  const float* __restrict__ new_xyz,
                                                  int* __restrict__ knn_idx) {
  const int q = blockIdx.x;  // b*S + s
  const int b = q / S_;
  __shared__ float sd[N_];  // 64 KB
  __shared__ float s_minv[4];
  __shared__ int s_mini[4];
  __shared__ int s_win;
  const int t = threadIdx.x;
  const float qx = new_xyz[q * 3 + 0];
  const float qy = new_xyz[q * 3 + 1];
  const float qz = new_xyz[q * 3 + 2];
  const float* X = xyz + (size_t)b * N_ * 3;
  float lmin = 1e30f;
  int lidx = -1;
  for (int j = 0; j < N_ / 256; ++j) {
    int i = t + j * 256;
    float dx = X[i * 3 + 0] - qx;
    float dy = X[i * 3 + 1] - qy;
    float dz = X[i * 3 + 2] - qz;
    float dsq = fmaf(dx, dx, fmaf(dy, dy, dz * dz));
    sd[i] = dsq;
    if (dsq < lmin) { lmin = dsq; lidx = i; }
  }
  __syncthreads();
  for (int r = 0; r < K_; ++r) {
    float v = lmin;
    int ii = lidx;
#pragma unroll
    for (int off = 32; off > 0; off >>= 1) {
      float ov = __shfl_down(v, off);
      int oi = __shfl_down(ii, off);
      if (ov < v) { v = ov; ii = oi; }
    }
    if ((t & 63) == 0) { s_minv[t >> 6] = v; s_mini[t >> 6] = ii; }
    __syncthreads();
    if (t == 0) {
      float bv = s_minv[0]; int bi = s_mini[0];
#pragma unroll
      for (int w = 1; w < 4; ++w)
        if (s_minv[w] < bv) { bv = s_minv[w]; bi = s_mini[w]; }
      knn_idx[q * K_ + r] = bi;
      s_win = bi;
    }
    __syncthreads();
    int wi = s_win;
    if (wi == lidx) {  // unique owner (disjoint index ranges per thread)
      sd[wi] = 1e30f;
      lmin = 1e30f; lidx = -1;
      for (int j = 0; j < N_ / 256; ++j) {
        int i = t + j * 256;
        float dv = sd[i];
        if (dv < lmin) { lmin = dv; lidx = i; }
      }
    }
  }
}

// ---------------------------------------------------------------------------
// Transpose weights into ws (coalesced per-channel access later) and zero the
// stats region (exactly 49152 elements == transpose work, handled same grid).
// ---------------------------------------------------------------------------
__global__ __launch_bounds__(256) void prep_kernel(const float* __restrict__ W1,
                                                   const float* __restrict__ W2,
                                                   float* __restrict__ W1t,
                                                   float* __restrict__ W2t,
                                                   float* __restrict__ stats) {
  int e = blockIdx.x * 256 + threadIdx.x;  // 0 .. 49151
  stats[e] = 0.0f;
  if (e < C1_ * C0_) {
    int co = e / C0_, c = e % C0_;
    W1t[c * C1_ + co] = W1[e];
  } else {
    int e2 = e - C1_ * C0_;
    int co = e2 / C1_, c = e2 % C1_;
    W2t[c * C2_ + co] = W2[e2];
  }
}

// ---------------------------------------------------------------------------
// conv1 stats: gather + conv1 (y1 pre-BN), accumulate per-channel sum/sumsq.
// Grid 1024 blocks x 8 queries each; slot-sliced atomics (64 slots).
// ---------------------------------------------------------------------------
__global__ __launch_bounds__(256) void conv1_stats_kernel(
    const float* __restrict__ xyz, const float* __restrict__ feat,
    const float* __restrict__ new_xyz, const int* __restrict__ knn,
    const float* __restrict__ W1t, const float* __restrict__ b1,
    float* __restrict__ stats1) {
  __shared__ __align__(16) float sinT[C0_][K_];  // transposed: [c][k]
  __shared__ int sidx[K_];
  __shared__ float sred[256];
  const int t = threadIdx.x;
  float psum = 0.f, psumsq = 0.f;
  const int QPB = (B_ * S_) / 1024;  // 8
  for (int qq = 0; qq < QPB; ++qq) {
    const int q = blockIdx.x * QPB + qq;
    const int b = q / S_;
    if (t < K_) sidx[t] = knn[q * K_ + t];
    __syncthreads();
    const float nx = new_xyz[q * 3 + 0];
    const float ny = new_xyz[q * 3 + 1];
    const float nz = new_xyz[q * 3 + 2];
    for (int e = t; e < K_ * C0_; e += 256) {
      int c = e >> 4, kk = e & 15;
      int i = sidx[kk];
      float v;
      if (c < 3)
        v = xyz[((size_t)b * N_ + i) * 3 + c] - (c == 0 ? nx : (c == 1 ? ny : nz));
      else
        v = feat[((size_t)b * N_ + i) * D_ + (c - 3)];
      sinT[c][kk] = v;
    }
    __syncthreads();
    const int co = t & 127, kh = t >> 7;
    float acc[8];
    float bias = b1[co];
#pragma unroll
    for (int k = 0; k < 8; ++k) acc[k] = bias;
    for (int c = 0; c < C0_; ++c) {
      float w = W1t[c * C1_ + co];
      float4 xa = *(const float4*)&sinT[c][kh * 8];
      float4 xb = *(const float4*)&sinT[c][kh * 8 + 4];
      acc[0] = fmaf(w, xa.x, acc[0]);
      acc[1] = fmaf(w, xa.y, acc[1]);
      acc[2] = fmaf(w, xa.z, acc[2]);
      acc[3] = fmaf(w, xa.w, acc[3]);
      acc[4] = fmaf(w, xb.x, acc[4]);
      acc[5] = fmaf(w, xb.y, acc[5]);
      acc[6] = fmaf(w, xb.z, acc[6]);
      acc[7] = fmaf(w, xb.w, acc[7]);
    }
#pragma unroll
    for (int k = 0; k < 8; ++k) {
      psum += acc[k];
      psumsq = fmaf(acc[k], acc[k], psumsq);
    }
    __syncthreads();
  }
  sred[t] = psum;
  __syncthreads();
  float totsum = (t < 128) ? (sred[t] + sred[t + 128]) : 0.f;
  __syncthreads();
  sred[t] = psumsq;
  __syncthreads();
  if (t < 128) {
    float totsq = sred[t] + sred[t + 128];
    float* st = stats1 + (size_t)(blockIdx.x & (NSLOT - 1)) * (2 * C1_);
    atomicAdd(&st[t], totsum);
    atomicAdd(&st[C1_ + t], totsq);
  }
}

__global__ void finalize1_kernel(const float* __restrict__ stats1,
                                 const float* __restrict__ gamma1,
                                 const float* __restrict__ beta1,
                                 float* __restrict__ ss1) {
  int t = threadIdx.x;  // 128
  float s = 0.f, sq = 0.f;
  for (int w = 0; w < NSLOT; ++w) {
    s += stats1[w * 2 * C1_ + t];
    sq += stats1[w * 2 * C1_ + C1_ + t];
  }
  const float M = (float)(B_ * S_ * K_);
  float m = s / M;
  float v = fmaxf(sq / M - m * m, 0.f);
  float sc = gamma1[t] * rsqrtf(v + 1e-5f);
  ss1[t] = sc;
  ss1[C1_ + t] = fmaf(-m, sc, beta1[t]);
}

// ---------------------------------------------------------------------------
// conv2: re-gather, recompute conv1, apply bn1+relu -> LDS, conv2, per-(q,co2)
// max/min over k, accumulate y2 stats. Grid 1024 x 8 queries.
// ---------------------------------------------------------------------------
__global__ __launch_bounds__(256) void conv2_kernel(
    const float* __restrict__ xyz, const float* __restrict__ feat,
    const float* __restrict__ new_xyz, const int* __restrict__ knn,
    const float* __restrict__ W1t, const float* __restrict__ b1,
    const float* __restrict__ ss1, const float* __restrict__ W2t,
    const float* __restrict__ b2, float* __restrict__ maxv,
    float* __restrict__ minv, float* __restrict__ stats2) {
  __shared__ __align__(16) float sinT[C0_][K_];
  __shared__ __align__(16) float sh1T[C1_][20];  // pad 16->20 (bank spread, 16B-aligned rows)
  __shared__ int sidx[K_];
  const int t = threadIdx.x;
  float psum = 0.f, psumsq = 0.f;
  const int QPB = (B_ * S_) / 1024;  // 8
  for (int qq = 0; qq < QPB; ++qq) {
    const int q = blockIdx.x * QPB + qq;
    const int b = q / S_;
    if (t < K_) sidx[t] = knn[q * K_ + t];
    __syncthreads();
    const float nx = new_xyz[q * 3 + 0];
    const float ny = new_xyz[q * 3 + 1];
    const float nz = new_xyz[q * 3 + 2];
    for (int e = t; e < K_ * C0_; e += 256) {
      int c = e >> 4, kk = e & 15;
      int i = sidx[kk];
      float v;
      if (c < 3)
        v = xyz[((size_t)b * N_ + i) * 3 + c] - (c == 0 ? nx : (c == 1 ? ny : nz));
      else
        v = feat[((size_t)b * N_ + i) * D_ + (c - 3)];
      sinT[c][kk] = v;
    }
    __syncthreads();
    {  // conv1 + bn1 + relu -> sh1T[c_in2][k]
      const int co = t & 127, kh = t >> 7;
      float acc[8];
      float bias = b1[co];
#pragma unroll
      for (int k = 0; k < 8; ++k) acc[k] = bias;
      for (int c = 0; c < C0_; ++c) {
        float w = W1t[c * C1_ + co];
        float4 xa = *(const float4*)&sinT[c][kh * 8];
        float4 xb = *(const float4*)&sinT[c][kh * 8 + 4];
        acc[0] = fmaf(w, xa.x, acc[0]);
        acc[1] = fmaf(w, xa.y, acc[1]);
        acc[2] = fmaf(w, xa.z, acc[2]);
        acc[3] = fmaf(w, xa.w, acc[3]);
        acc[4] = fmaf(w, xb.x, acc[4]);
        acc[5] = fmaf(w, xb.y, acc[5]);
        acc[6] = fmaf(w, xb.z, acc[6]);
        acc[7] = fmaf(w, xb.w, acc[7]);
      }
      float sc = ss1[co], sh = ss1[C1_ + co];
#pragma unroll
      for (int k = 0; k < 8; ++k) {
        float h = fmaxf(fmaf(acc[k], sc, sh), 0.f);
        sh1T[co][kh * 8 + k] = h;
      }
    }
    __syncthreads();
    {  // conv2: thread t -> co2 = t
      float acc2[16];
      float bias2 = b2[t];
#pragma unroll
      for (int k = 0; k < 16; ++k) acc2[k] = bias2;
      for (int c = 0; c < C1_; ++c) {
        float w = W2t[c * C2_ + t];
        float4 h0 = *(const float4*)&sh1T[c][0];
        float4 h1 = *(const float4*)&sh1T[c][4];
        float4 h2 = *(const float4*)&sh1T[c][8];
        float4 h3 = *(const float4*)&sh1T[c][12];
        acc2[0] = fmaf(w, h0.x, acc2[0]);
        acc2[1] = fmaf(w, h0.y, acc2[1]);
        acc2[2] = fmaf(w, h0.z, acc2[2]);
        acc2[3] = fmaf(w, h0.w, acc2[3]);
        acc2[4] = fmaf(w, h1.x, acc2[4]);
        acc2[5] = fmaf(w, h1.y, acc2[5]);
        acc2[6] = fmaf(w, h1.z, acc2[6]);
        acc2[7] = fmaf(w, h1.w, acc2[7]);
        acc2[8] = fmaf(w, h2.x, acc2[8]);
        acc2[9] = fmaf(w, h2.y, acc2[9]);
        acc2[10] = fmaf(w, h2.z, acc2[10]);
        acc2[11] = fmaf(w, h2.w, acc2[11]);
        acc2[12] = fmaf(w, h3.x, acc2[12]);
        acc2[13] = fmaf(w, h3.y, acc2[13]);
        acc2[14] = fmaf(w, h3.z, acc2[14]);
        acc2[15] = fmaf(w, h3.w, acc2[15]);
      }
      float mx = acc2[0], mn = acc2[0];
#pragma unroll
      for (int k = 0; k < 16; ++k) {
        psum += acc2[k];
        psumsq = fmaf(acc2[k], acc2[k], psumsq);
        mx = fmaxf(mx, acc2[k]);
        mn = fminf(mn, acc2[k]);
      }
      maxv[(size_t)q * C2_ + t] = mx;
      minv[(size_t)q * C2_ + t] = mn;
    }
    __syncthreads();
  }
  float* st = stats2 + (size_t)(blockIdx.x & (NSLOT - 1)) * (2 * C2_);
  atomicAdd(&st[t], psum);
  atomicAdd(&st[C2_ + t], psumsq);
}

__global__ void finalize2_kernel(const float* __restrict__ stats2,
                                 const float* __restrict__ gamma2,
                                 const float* __restrict__ beta2,
                                 float* __restrict__ ss2) {
  int t = threadIdx.x;  // 256
  float s = 0.f, sq = 0.f;
  for (int w = 0; w < NSLOT; ++w) {
    s += stats2[w * 2 * C2_ + t];
    sq += stats2[w * 2 * C2_ + C2_ + t];
  }
  const float M = (float)(B_ * S_ * K_);
  float m = s / M;
  float v = fmaxf(sq / M - m * m, 0.f);
  float sc = gamma2[t] * rsqrtf(v + 1e-5f);
  ss2[t] = sc;
  ss2[C2_ + t] = fmaf(-m, sc, beta2[t]);
}

// max_k relu(bn(y)) == relu(bn(max_k y)) for scale>=0 (min_k for scale<0)
__global__ __launch_bounds__(256) void out_kernel(const float* __restrict__ maxv,
                                                  const float* __restrict__ minv,
                                                  const float* __restrict__ ss2,
                                                  float* __restrict__ out2) {
  int e = blockIdx.x * 256 + threadIdx.x;
  int co = e & (C2_ - 1);
  float sc = ss2[co], sh = ss2[C2_ + co];
  float v = (sc >= 0.f) ? maxv[e] : minv[e];
  out2[e] = fmaxf(fmaf(v, sc, sh), 0.f);
}

extern "C" void kernel_launch(void* const* d_in, const int* in_sizes, int n_in,
                              void* d_out, int out_size, void* d_ws, size_t ws_size,
                              hipStream_t stream) {
  (void)in_sizes; (void)n_in; (void)out_size; (void)ws_size;
  const float* xyz = (const float*)d_in[0];
  const float* feat = (const float*)d_in[1];
  const float* W1 = (const float*)d_in[2];
  const float* b1 = (const float*)d_in[3];
  const float* gamma1 = (const float*)d_in[4];
  const float* beta1 = (const float*)d_in[5];
  const float* W2 = (const float*)d_in[6];
  const float* b2 = (const float*)d_in[7];
  const float* gamma2 = (const float*)d_in[8];
  const float* beta2 = (const float*)d_in[9];

  float* out = (float*)d_out;
  float* new_xyz = out;                 // [B,S,3]
  float* out2 = out + B_ * S_ * 3;      // [B,S,C2]

  float* ws = (float*)d_ws;
  float* stats1 = ws;                              // 64*256
  float* stats2 = stats1 + NSLOT * 2 * C1_;        // 64*512
  float* ss1 = stats2 + NSLOT * 2 * C2_;           // 256
  float* ss2 = ss1 + 2 * C1_;                      // 512
  float* W1t = ss2 + 2 * C2_;                      // 16384
  float* W2t = W1t + C1_ * C0_;                    // 32768
  int* knn = (int*)(W2t + (size_t)C2_ * C1_);      // B*S*K ints
  float* maxv = (float*)(knn + B_ * S_ * K_);      // B*S*C2
  float* minv = maxv + (size_t)B_ * S_ * C2_;      // B*S*C2

  prep_kernel<<<192, 256, 0, stream>>>(W1, W2, W1t, W2t, stats1);
  fps_kernel<<<B_, 512, 0, stream>>>(xyz, new_xyz);
  knn_kernel<<<B_ * S_, 256, 0, stream>>>(xyz, new_xyz, knn);
  conv1_stats_kernel<<<1024, 256, 0, stream>>>(xyz, feat, new_xyz, knn, W1t, b1, stats1);
  finalize1_kernel<<<1, 128, 0, stream>>>(stats1, gamma1, beta1, ss1);
  conv2_kernel<<<1024, 256, 0, stream>>>(xyz, feat, new_xyz, knn, W1t, b1, ss1,
                                         W2t, b2, maxv, minv, stats2);
  finalize2_kernel<<<1, 256, 0, stream>>>(stats2, gamma2, beta2, ss2);
  out_kernel<<<(B_ * S_ * C2_) / 256, 256, 0, stream>>>(maxv, minv, ss2, out2);
}

// Round 5
// 5005.924 us; speedup vs baseline: 1.1722x; 1.0699x over previous
//
#include <hip/hip_runtime.h>

#define B_ 4
#define N_ 16384
#define D_ 125
#define S_ 2048
#define K_ 16
#define C0_ 128
#define C1_ 128
#define C2_ 256
#define NSLOT 64

typedef float v2f __attribute__((ext_vector_type(2)));

// Opaque-ify a float so the compiler cannot rematerialize it from memory.
__device__ __forceinline__ void pin(float& x) { asm volatile("" : "+v"(x)); }

// ---------------------------------------------------------------------------
// FPS: one block per batch, 512 threads, 32 points/thread in registers.
// amdgpu_waves_per_eu(2,2) pins BOTH min and max occupancy, so the register
// allocator's desired-occupancy heuristic (which capped us at 84 VGPR = 6
// waves/EU for three rounds, spilling/rematerializing all 96 coordinate
// values every iteration) finally allows ~200 VGPRs: the hot loop runs
// load-free except the centroid broadcast.
// Bit-exact vs numpy: contract(off) keeps mul/mul/add/add rounding, fminf,
// argmax with first-index tie-break at every level (lowest matching lane =
// smallest point index since per-lane ranges are ordered and disjoint).
// ---------------------------------------------------------------------------
__global__ __attribute__((amdgpu_flat_work_group_size(512, 512),
                          amdgpu_waves_per_eu(2, 2)))
void fps_kernel(const float* __restrict__ xyz, float* __restrict__ new_xyz) {
#pragma clang fp contract(off)
  const int b = blockIdx.x;
  const float* X = xyz + (size_t)b * N_ * 3;
  const int t = threadIdx.x;
  constexpr int PAIRS = N_ / 512 / 2;  // 16 pairs = 32 points/thread
  v2f px[PAIRS], py[PAIRS], pz[PAIRS], d[PAIRS];
  const int base = t * (2 * PAIRS);
#pragma unroll
  for (int j = 0; j < PAIRS; ++j) {
    const int i0 = (base + 2 * j) * 3;
    px[j] = (v2f){X[i0 + 0], X[i0 + 3]};
    py[j] = (v2f){X[i0 + 1], X[i0 + 4]};
    pz[j] = (v2f){X[i0 + 2], X[i0 + 5]};
    d[j] = (v2f){1e10f, 1e10f};
  }
  // Pin coordinates into registers (blocks rematerialization from memory).
#pragma unroll
  for (int j = 0; j < PAIRS; ++j) {
    float a0 = px[j].x, a1 = px[j].y;
    float b0 = py[j].x, b1 = py[j].y;
    float c0 = pz[j].x, c1 = pz[j].y;
    pin(a0); pin(a1); pin(b0); pin(b1); pin(c0); pin(c1);
    px[j] = (v2f){a0, a1};
    py[j] = (v2f){b0, b1};
    pz[j] = (v2f){c0, c1};
  }
  __shared__ float s_val[2][8];
  __shared__ int s_idx[2][8];
  float cx = X[0], cy = X[1], cz = X[2];  // centroid 0 (broadcast load, once)
  float cap_x = 0.f, cap_y = 0.f, cap_z = 0.f;  // per-thread output capture
  for (int s = 0; s < S_; ++s) {
    if (((s - t) & 511) == 0) { cap_x = cx; cap_y = cy; cap_z = cz; }  // s%512==t
    if ((s & 511) == 511) {  // epoch flush: 512 coalesced centroids
      const int o = (b * S_ + (s & ~511) + t) * 3;
      new_xyz[o + 0] = cap_x;
      new_xyz[o + 1] = cap_y;
      new_xyz[o + 2] = cap_z;
    }
    if (s == S_ - 1) break;  // last index needs no further update
    const v2f c2x = {cx, cx}, c2y = {cy, cy}, c2z = {cz, cz};
    // ---- phase 1: value-only update (packed, register-resident) ----
    v2f m2 = {-1.0f, -1.0f};
#pragma unroll
    for (int j = 0; j < PAIRS; ++j) {
      v2f dx = px[j] - c2x;
      v2f dy = py[j] - c2y;
      v2f dz = pz[j] - c2z;
      v2f sq = (dx * dx + dy * dy) + dz * dz;  // contract(off): exact ref order
      v2f dm;
      dm.x = fminf(d[j].x, sq.x);
      dm.y = fminf(d[j].y, sq.y);
      d[j] = dm;
      m2.x = fmaxf(m2.x, dm.x);
      m2.y = fmaxf(m2.y, dm.y);
    }
    const float lmax = fmaxf(m2.x, m2.y);
    // ---- phase 2: recover first (smallest) local index attaining lmax ----
    int lidx = 0x7fffffff;
#pragma unroll
    for (int j = 0; j < PAIRS; ++j) {
      if (d[j].x == lmax) lidx = min(lidx, base + 2 * j);
      if (d[j].y == lmax) lidx = min(lidx, base + 2 * j + 1);
    }
    // ---- wave argmax: value butterfly, then lowest matching lane's index ----
    float wmax = lmax;
#pragma unroll
    for (int off = 32; off > 0; off >>= 1)
      wmax = fmaxf(wmax, __shfl_xor(wmax, off));
    unsigned long long mask = __ballot(lmax == wmax);
    int src = __ffsll(mask) - 1;
    int widx = __shfl(lidx, src);
    const int buf = s & 1;
    if ((t & 63) == 0) { s_val[buf][t >> 6] = wmax; s_idx[buf][t >> 6] = widx; }
    __syncthreads();
    // all threads redundantly scan the 8 partials (broadcast LDS reads)
    float bv = s_val[buf][0];
    int bi = s_idx[buf][0];
#pragma unroll
    for (int w = 1; w < 8; ++w) {
      float v = s_val[buf][w];
      int i = s_idx[buf][w];
      if (v > bv || (v == bv && i < bi)) { bv = v; bi = i; }
    }
    // centroid for next iter (same address across lanes -> broadcast, L2-hot)
    cx = X[bi * 3 + 0];
    cy = X[bi * 3 + 1];
    cz = X[bi * 3 + 2];
  }
}

// ---------------------------------------------------------------------------
// kNN: one block (256 thr) per query. Distances in LDS; 16 rounds of
// block-min with winner-only local rescan. Set semantics (order irrelevant).
// ---------------------------------------------------------------------------
__global__ __launch_bounds__(256) void knn_kernel(const float* __restrict__ xyz,
                                                  const float* __restrict__ new_xyz,
                                                  int* __restrict__ knn_idx) {
  const int q = blockIdx.x;  // b*S + s
  const int b = q / S_;
  __shared__ float sd[N_];  // 64 KB
  __shared__ float s_minv[4];
  __shared__ int s_mini[4];
  __shared__ int s_win;
  const int t = threadIdx.x;
  const float qx = new_xyz[q * 3 + 0];
  const float qy = new_xyz[q * 3 + 1];
  const float qz = new_xyz[q * 3 + 2];
  const float* X = xyz + (size_t)b * N_ * 3;
  float lmin = 1e30f;
  int lidx = -1;
  for (int j = 0; j < N_ / 256; ++j) {
    int i = t + j * 256;
    float dx = X[i * 3 + 0] - qx;
    float dy = X[i * 3 + 1] - qy;
    float dz = X[i * 3 + 2] - qz;
    float dsq = fmaf(dx, dx, fmaf(dy, dy, dz * dz));
    sd[i] = dsq;
    if (dsq < lmin) { lmin = dsq; lidx = i; }
  }
  __syncthreads();
  for (int r = 0; r < K_; ++r) {
    float v = lmin;
    int ii = lidx;
#pragma unroll
    for (int off = 32; off > 0; off >>= 1) {
      float ov = __shfl_down(v, off);
      int oi = __shfl_down(ii, off);
      if (ov < v) { v = ov; ii = oi; }
    }
    if ((t & 63) == 0) { s_minv[t >> 6] = v; s_mini[t >> 6] = ii; }
    __syncthreads();
    if (t == 0) {
      float bv = s_minv[0]; int bi = s_mini[0];
#pragma unroll
      for (int w = 1; w < 4; ++w)
        if (s_minv[w] < bv) { bv = s_minv[w]; bi = s_mini[w]; }
      knn_idx[q * K_ + r] = bi;
      s_win = bi;
    }
    __syncthreads();
    int wi = s_win;
    if (wi == lidx) {  // unique owner (disjoint index ranges per thread)
      sd[wi] = 1e30f;
      lmin = 1e30f; lidx = -1;
      for (int j = 0; j < N_ / 256; ++j) {
        int i = t + j * 256;
        float dv = sd[i];
        if (dv < lmin) { lmin = dv; lidx = i; }
      }
    }
  }
}

// ---------------------------------------------------------------------------
// Transpose weights into ws (coalesced per-channel access later) and zero the
// stats region (exactly 49152 elements == transpose work, handled same grid).
// ---------------------------------------------------------------------------
__global__ __launch_bounds__(256) void prep_kernel(const float* __restrict__ W1,
                                                   const float* __restrict__ W2,
                                                   float* __restrict__ W1t,
                                                   float* __restrict__ W2t,
                                                   float* __restrict__ stats) {
  int e = blockIdx.x * 256 + threadIdx.x;  // 0 .. 49151
  stats[e] = 0.0f;
  if (e < C1_ * C0_) {
    int co = e / C0_, c = e % C0_;
    W1t[c * C1_ + co] = W1[e];
  } else {
    int e2 = e - C1_ * C0_;
    int co = e2 / C1_, c = e2 % C1_;
    W2t[c * C2_ + co] = W2[e2];
  }
}

// ---------------------------------------------------------------------------
// conv1 stats: gather + conv1 (y1 pre-BN), accumulate per-channel sum/sumsq.
// Grid 1024 blocks x 8 queries each; slot-sliced atomics (64 slots).
// ---------------------------------------------------------------------------
__global__ __launch_bounds__(256) void conv1_stats_kernel(
    const float* __restrict__ xyz, const float* __restrict__ feat,
    const float* __restrict__ new_xyz, const int* __restrict__ knn,
    const float* __restrict__ W1t, const float* __restrict__ b1,
    float* __restrict__ stats1) {
  __shared__ __align__(16) float sinT[C0_][K_];  // transposed: [c][k]
  __shared__ int sidx[K_];
  __shared__ float sred[256];
  const int t = threadIdx.x;
  float psum = 0.f, psumsq = 0.f;
  const int QPB = (B_ * S_) / 1024;  // 8
  for (int qq = 0; qq < QPB; ++qq) {
    const int q = blockIdx.x * QPB + qq;
    const int b = q / S_;
    if (t < K_) sidx[t] = knn[q * K_ + t];
    __syncthreads();
    const float nx = new_xyz[q * 3 + 0];
    const float ny = new_xyz[q * 3 + 1];
    const float nz = new_xyz[q * 3 + 2];
    for (int e = t; e < K_ * C0_; e += 256) {
      int c = e >> 4, kk = e & 15;
      int i = sidx[kk];
      float v;
      if (c < 3)
        v = xyz[((size_t)b * N_ + i) * 3 + c] - (c == 0 ? nx : (c == 1 ? ny : nz));
      else
        v = feat[((size_t)b * N_ + i) * D_ + (c - 3)];
      sinT[c][kk] = v;
    }
    __syncthreads();
    const int co = t & 127, kh = t >> 7;
    float acc[8];
    float bias = b1[co];
#pragma unroll
    for (int k = 0; k < 8; ++k) acc[k] = bias;
    for (int c = 0; c < C0_; ++c) {
      float w = W1t[c * C1_ + co];
      float4 xa = *(const float4*)&sinT[c][kh * 8];
      float4 xb = *(const float4*)&sinT[c][kh * 8 + 4];
      acc[0] = fmaf(w, xa.x, acc[0]);
      acc[1] = fmaf(w, xa.y, acc[1]);
      acc[2] = fmaf(w, xa.z, acc[2]);
      acc[3] = fmaf(w, xa.w, acc[3]);
      acc[4] = fmaf(w, xb.x, acc[4]);
      acc[5] = fmaf(w, xb.y, acc[5]);
      acc[6] = fmaf(w, xb.z, acc[6]);
      acc[7] = fmaf(w, xb.w, acc[7]);
    }
#pragma unroll
    for (int k = 0; k < 8; ++k) {
      psum += acc[k];
      psumsq = fmaf(acc[k], acc[k], psumsq);
    }
    __syncthreads();
  }
  sred[t] = psum;
  __syncthreads();
  float totsum = (t < 128) ? (sred[t] + sred[t + 128]) : 0.f;
  __syncthreads();
  sred[t] = psumsq;
  __syncthreads();
  if (t < 128) {
    float totsq = sred[t] + sred[t + 128];
    float* st = stats1 + (size_t)(blockIdx.x & (NSLOT - 1)) * (2 * C1_);
    atomicAdd(&st[t], totsum);
    atomicAdd(&st[C1_ + t], totsq);
  }
}

__global__ void finalize1_kernel(const float* __restrict__ stats1,
                                 const float* __restrict__ gamma1,
                                 const float* __restrict__ beta1,
                                 float* __restrict__ ss1) {
  int t = threadIdx.x;  // 128
  float s = 0.f, sq = 0.f;
  for (int w = 0; w < NSLOT; ++w) {
    s += stats1[w * 2 * C1_ + t];
    sq += stats1[w * 2 * C1_ + C1_ + t];
  }
  const float M = (float)(B_ * S_ * K_);
  float m = s / M;
  float v = fmaxf(sq / M - m * m, 0.f);
  float sc = gamma1[t] * rsqrtf(v + 1e-5f);
  ss1[t] = sc;
  ss1[C1_ + t] = fmaf(-m, sc, beta1[t]);
}

// ---------------------------------------------------------------------------
// conv2: re-gather, recompute conv1, apply bn1+relu -> LDS, conv2, per-(q,co2)
// max/min over k, accumulate y2 stats. Grid 1024 x 8 queries.
// ---------------------------------------------------------------------------
__global__ __launch_bounds__(256) void conv2_kernel(
    const float* __restrict__ xyz, const float* __restrict__ feat,
    const float* __restrict__ new_xyz, const int* __restrict__ knn,
    const float* __restrict__ W1t, const float* __restrict__ b1,
    const float* __restrict__ ss1, const float* __restrict__ W2t,
    const float* __restrict__ b2, float* __restrict__ maxv,
    float* __restrict__ minv, float* __restrict__ stats2) {
  __shared__ __align__(16) float sinT[C0_][K_];
  __shared__ __align__(16) float sh1T[C1_][20];  // pad 16->20 (bank spread, 16B-aligned rows)
  __shared__ int sidx[K_];
  const int t = threadIdx.x;
  float psum = 0.f, psumsq = 0.f;
  const int QPB = (B_ * S_) / 1024;  // 8
  for (int qq = 0; qq < QPB; ++qq) {
    const int q = blockIdx.x * QPB + qq;
    const int b = q / S_;
    if (t < K_) sidx[t] = knn[q * K_ + t];
    __syncthreads();
    const float nx = new_xyz[q * 3 + 0];
    const float ny = new_xyz[q * 3 + 1];
    const float nz = new_xyz[q * 3 + 2];
    for (int e = t; e < K_ * C0_; e += 256) {
      int c = e >> 4, kk = e & 15;
      int i = sidx[kk];
      float v;
      if (c < 3)
        v = xyz[((size_t)b * N_ + i) * 3 + c] - (c == 0 ? nx : (c == 1 ? ny : nz));
      else
        v = feat[((size_t)b * N_ + i) * D_ + (c - 3)];
      sinT[c][kk] = v;
    }
    __syncthreads();
    {  // conv1 + bn1 + relu -> sh1T[c_in2][k]
      const int co = t & 127, kh = t >> 7;
      float acc[8];
      float bias = b1[co];
#pragma unroll
      for (int k = 0; k < 8; ++k) acc[k] = bias;
      for (int c = 0; c < C0_; ++c) {
        float w = W1t[c * C1_ + co];
        float4 xa = *(const float4*)&sinT[c][kh * 8];
        float4 xb = *(const float4*)&sinT[c][kh * 8 + 4];
        acc[0] = fmaf(w, xa.x, acc[0]);
        acc[1] = fmaf(w, xa.y, acc[1]);
        acc[2] = fmaf(w, xa.z, acc[2]);
        acc[3] = fmaf(w, xa.w, acc[3]);
        acc[4] = fmaf(w, xb.x, acc[4]);
        acc[5] = fmaf(w, xb.y, acc[5]);
        acc[6] = fmaf(w, xb.z, acc[6]);
        acc[7] = fmaf(w, xb.w, acc[7]);
      }
      float sc = ss1[co], sh = ss1[C1_ + co];
#pragma unroll
      for (int k = 0; k < 8; ++k) {
        float h = fmaxf(fmaf(acc[k], sc, sh), 0.f);
        sh1T[co][kh * 8 + k] = h;
      }
    }
    __syncthreads();
    {  // conv2: thread t -> co2 = t
      float acc2[16];
      float bias2 = b2[t];
#pragma unroll
      for (int k = 0; k < 16; ++k) acc2[k] = bias2;
      for (int c = 0; c < C1_; ++c) {
        float w = W2t[c * C2_ + t];
        float4 h0 = *(const float4*)&sh1T[c][0];
        float4 h1 = *(const float4*)&sh1T[c][4];
        float4 h2 = *(const float4*)&sh1T[c][8];
        float4 h3 = *(const float4*)&sh1T[c][12];
        acc2[0] = fmaf(w, h0.x, acc2[0]);
        acc2[1] = fmaf(w, h0.y, acc2[1]);
        acc2[2] = fmaf(w, h0.z, acc2[2]);
        acc2[3] = fmaf(w, h0.w, acc2[3]);
        acc2[4] = fmaf(w, h1.x, acc2[4]);
        acc2[5] = fmaf(w, h1.y, acc2[5]);
        acc2[6] = fmaf(w, h1.z, acc2[6]);
        acc2[7] = fmaf(w, h1.w, acc2[7]);
        acc2[8] = fmaf(w, h2.x, acc2[8]);
        acc2[9] = fmaf(w, h2.y, acc2[9]);
        acc2[10] = fmaf(w, h2.z, acc2[10]);
        acc2[11] = fmaf(w, h2.w, acc2[11]);
        acc2[12] = fmaf(w, h3.x, acc2[12]);
        acc2[13] = fmaf(w, h3.y, acc2[13]);
        acc2[14] = fmaf(w, h3.z, acc2[14]);
        acc2[15] = fmaf(w, h3.w, acc2[15]);
      }
      float mx = acc2[0], mn = acc2[0];
#pragma unroll
      for (int k = 0; k < 16; ++k) {
        psum += acc2[k];
        psumsq = fmaf(acc2[k], acc2[k], psumsq);
        mx = fmaxf(mx, acc2[k]);
        mn = fminf(mn, acc2[k]);
      }
      maxv[(size_t)q * C2_ + t] = mx;
      minv[(size_t)q * C2_ + t] = mn;
    }
    __syncthreads();
  }
  float* st = stats2 + (size_t)(blockIdx.x & (NSLOT - 1)) * (2 * C2_);
  atomicAdd(&st[t], psum);
  atomicAdd(&st[C2_ + t], psumsq);
}

__global__ void finalize2_kernel(const float* __restrict__ stats2,
                                 const float* __restrict__ gamma2,
                                 const float* __restrict__ beta2,
                                 float* __restrict__ ss2) {
  int t = threadIdx.x;  // 256
  float s = 0.f, sq = 0.f;
  for (int w = 0; w < NSLOT; ++w) {
    s += stats2[w * 2 * C2_ + t];
    sq += stats2[w * 2 * C2_ + C2_ + t];
  }
  const float M = (float)(B_ * S_ * K_);
  float m = s / M;
  float v = fmaxf(sq / M - m * m, 0.f);
  float sc = gamma2[t] * rsqrtf(v + 1e-5f);
  ss2[t] = sc;
  ss2[C2_ + t] = fmaf(-m, sc, beta2[t]);
}

// max_k relu(bn(y)) == relu(bn(max_k y)) for scale>=0 (min_k for scale<0)
__global__ __launch_bounds__(256) void out_kernel(const float* __restrict__ maxv,
                                                  const float* __restrict__ minv,
                                                  const float* __restrict__ ss2,
                                                  float* __restrict__ out2) {
  int e = blockIdx.x * 256 + threadIdx.x;
  int co = e & (C2_ - 1);
  float sc = ss2[co], sh = ss2[C2_ + co];
  float v = (sc >= 0.f) ? maxv[e] : minv[e];
  out2[e] = fmaxf(fmaf(v, sc, sh), 0.f);
}

extern "C" void kernel_launch(void* const* d_in, const int* in_sizes, int n_in,
                              void* d_out, int out_size, void* d_ws, size_t ws_size,
                              hipStream_t stream) {
  (void)in_sizes; (void)n_in; (void)out_size; (void)ws_size;
  const float* xyz = (const float*)d_in[0];
  const float* feat = (const float*)d_in[1];
  const float* W1 = (const float*)d_in[2];
  const float* b1 = (const float*)d_in[3];
  const float* gamma1 = (const float*)d_in[4];
  const float* beta1 = (const float*)d_in[5];
  const float* W2 = (const float*)d_in[6];
  const float* b2 = (const float*)d_in[7];
  const float* gamma2 = (const float*)d_in[8];
  const float* beta2 = (const float*)d_in[9];

  float* out = (float*)d_out;
  float* new_xyz = out;                 // [B,S,3]
  float* out2 = out + B_ * S_ * 3;      // [B,S,C2]

  float* ws = (float*)d_ws;
  float* stats1 = ws;                              // 64*256
  float* stats2 = stats1 + NSLOT * 2 * C1_;        // 64*512
  float* ss1 = stats2 + NSLOT * 2 * C2_;           // 256
  float* ss2 = ss1 + 2 * C1_;                      // 512
  float* W1t = ss2 + 2 * C2_;                      // 16384
  float* W2t = W1t + C1_ * C0_;                    // 32768
  int* knn = (int*)(W2t + (size_t)C2_ * C1_);      // B*S*K ints
  float* maxv = (float*)(knn + B_ * S_ * K_);      // B*S*C2
  float* minv = maxv + (size_t)B_ * S_ * C2_;      // B*S*C2

  prep_kernel<<<192, 256, 0, stream>>>(W1, W2, W1t, W2t, stats1);
  fps_kernel<<<B_, 512, 0, stream>>>(xyz, new_xyz);
  knn_kernel<<<B_ * S_, 256, 0, stream>>>(xyz, new_xyz, knn);
  conv1_stats_kernel<<<1024, 256, 0, stream>>>(xyz, feat, new_xyz, knn, W1t, b1, stats1);
  finalize1_kernel<<<1, 128, 0, stream>>>(stats1, gamma1, beta1, ss1);
  conv2_kernel<<<1024, 256, 0, stream>>>(xyz, feat, new_xyz, knn, W1t, b1, ss1,
                                         W2t, b2, maxv, minv, stats2);
  finalize2_kernel<<<1, 256, 0, stream>>>(stats2, gamma2, beta2, ss2);
  out_kernel<<<(B_ * S_ * C2_) / 256, 256, 0, stream>>>(maxv, minv, ss2, out2);
}

// Round 6
// 4284.185 us; speedup vs baseline: 1.3696x; 1.1685x over previous
//
#include <hip/hip_runtime.h>

#define B_ 4
#define N_ 16384
#define D_ 125
#define S_ 2048
#define K_ 16
#define C0_ 128
#define C1_ 128
#define C2_ 256
#define NSLOT 64

typedef float v2f __attribute__((ext_vector_type(2)));

// Opaque-ify a float so the compiler cannot rematerialize it from memory.
__device__ __forceinline__ void pin(float& x) { asm volatile("" : "+v"(x)); }

// ---------------------------------------------------------------------------
// FPS: one block per batch, 1024 threads, 16 points/thread (8 v2f pairs).
// Round 2-5 lesson: the allocator refuses large residency asks (granted 96 of
// 256 allowed for a ~160-VGPR ask). At 1024 threads the full state is only
// ~64 VGPRs + temps (~90 total) vs a 128 cap -> grantable.
// Reduction: value-only shfl_xor butterfly; wave maxima to LDS; all threads
// scan 16 floats; ONLY threads holding the block max rescan their d[] and
// atomicMin the global point index (exact numpy first-index tie-break).
// Bit-exact vs numpy: contract(off) keeps mul/mul/add/add rounding, fminf.
// ---------------------------------------------------------------------------
__global__ __attribute__((amdgpu_flat_work_group_size(1024, 1024),
                          amdgpu_waves_per_eu(4, 4)))
void fps_kernel(const float* __restrict__ xyz, float* __restrict__ new_xyz) {
#pragma clang fp contract(off)
  const int b = blockIdx.x;
  const float* X = xyz + (size_t)b * N_ * 3;
  const int t = threadIdx.x;
  constexpr int PAIRS = N_ / 1024 / 2;  // 8 pairs = 16 points/thread
  v2f px[PAIRS], py[PAIRS], pz[PAIRS], d[PAIRS];
  const int base = t * (2 * PAIRS);
  {  // staging: 12 x float4 = 48 contiguous floats (16-B aligned: 192*t bytes)
    float arr[48];
    float4* a4 = (float4*)arr;
#pragma unroll
    for (int i = 0; i < 12; ++i) a4[i] = *(const float4*)(X + base * 3 + 4 * i);
#pragma unroll
    for (int j = 0; j < PAIRS; ++j) {
      px[j] = (v2f){arr[6 * j + 0], arr[6 * j + 3]};
      py[j] = (v2f){arr[6 * j + 1], arr[6 * j + 4]};
      pz[j] = (v2f){arr[6 * j + 2], arr[6 * j + 5]};
      d[j] = (v2f){1e10f, 1e10f};
    }
  }
  // Pin coordinates into registers (blocks rematerialization from memory).
#pragma unroll
  for (int j = 0; j < PAIRS; ++j) {
    float a0 = px[j].x, a1 = px[j].y;
    float b0 = py[j].x, b1 = py[j].y;
    float c0 = pz[j].x, c1 = pz[j].y;
    pin(a0); pin(a1); pin(b0); pin(b1); pin(c0); pin(c1);
    px[j] = (v2f){a0, a1};
    py[j] = (v2f){b0, b1};
    pz[j] = (v2f){c0, c1};
  }
  __shared__ __align__(16) float s_wmax[2][16];
  __shared__ int s_widx[2];
  if (t == 0) { s_widx[0] = 0x7fffffff; s_widx[1] = 0x7fffffff; }
  float cx = X[0], cy = X[1], cz = X[2];  // centroid 0 (broadcast load, once)
  float cap_x = 0.f, cap_y = 0.f, cap_z = 0.f;  // per-thread output capture
  for (int s = 0; s < S_; ++s) {
    if (((s - t) & 1023) == 0) { cap_x = cx; cap_y = cy; cap_z = cz; }
    if ((s & 1023) == 1023) {  // epoch flush: 1024 coalesced centroids
      const int o = (b * S_ + (s & ~1023) + t) * 3;
      new_xyz[o + 0] = cap_x;
      new_xyz[o + 1] = cap_y;
      new_xyz[o + 2] = cap_z;
    }
    if (s == S_ - 1) break;  // last index needs no further update
    const int buf = s & 1;
    const v2f c2x = {cx, cx}, c2y = {cy, cy}, c2z = {cz, cz};
    // ---- phase 1: value-only update (packed, register-resident) ----
    v2f m2 = {-1.0f, -1.0f};
#pragma unroll
    for (int j = 0; j < PAIRS; ++j) {
      v2f dx = px[j] - c2x;
      v2f dy = py[j] - c2y;
      v2f dz = pz[j] - c2z;
      v2f sq = (dx * dx + dy * dy) + dz * dz;  // contract(off): exact ref order
      v2f dm;
      dm.x = fminf(d[j].x, sq.x);
      dm.y = fminf(d[j].y, sq.y);
      d[j] = dm;
      m2.x = fmaxf(m2.x, dm.x);
      m2.y = fmaxf(m2.y, dm.y);
    }
    const float lmax = fmaxf(m2.x, m2.y);
    // ---- wave max (value only) ----
    float wv = lmax;
#pragma unroll
    for (int off = 32; off > 0; off >>= 1)
      wv = fmaxf(wv, __shfl_xor(wv, off));
    if ((t & 63) == 0) s_wmax[buf][t >> 6] = wv;
    __syncthreads();
    // ---- block max: every thread scans the 16 wave maxima ----
    const float4* W4 = (const float4*)s_wmax[buf];
    float4 w0 = W4[0], w1 = W4[1], w2 = W4[2], w3 = W4[3];
    float bv = fmaxf(fmaxf(fmaxf(w0.x, w0.y), fmaxf(w0.z, w0.w)),
                     fmaxf(fmaxf(w1.x, w1.y), fmaxf(w1.z, w1.w)));
    bv = fmaxf(bv, fmaxf(fmaxf(fmaxf(w2.x, w2.y), fmaxf(w2.z, w2.w)),
                         fmaxf(fmaxf(w3.x, w3.y), fmaxf(w3.z, w3.w))));
    // reset the idle buffer (untouched by anyone between the two barriers)
    if (t == 0) s_widx[1 - buf] = 0x7fffffff;
    // ---- only block-max holders recover & publish the min point index ----
    if (lmax == bv) {
      int lidx = 0x7fffffff;
#pragma unroll
      for (int j = 0; j < PAIRS; ++j) {
        if (d[j].x == bv) lidx = min(lidx, base + 2 * j);
        if (d[j].y == bv) lidx = min(lidx, base + 2 * j + 1);
      }
      atomicMin(&s_widx[buf], lidx);
    }
    __syncthreads();
    const int bi = s_widx[buf];
    // centroid for next iter (same address across lanes -> broadcast, L2-hot)
    cx = X[bi * 3 + 0];
    cy = X[bi * 3 + 1];
    cz = X[bi * 3 + 2];
  }
}

// ---------------------------------------------------------------------------
// kNN: one block (256 thr) per query. Distances in LDS; 16 rounds of
// block-min with winner-only local rescan. Set semantics (order irrelevant).
// ---------------------------------------------------------------------------
__global__ __launch_bounds__(256) void knn_kernel(const float* __restrict__ xyz,
                                                  const float* __restrict__ new_xyz,
                                                  int* __restrict__ knn_idx) {
  const int q = blockIdx.x;  // b*S + s
  const int b = q / S_;
  __shared__ float sd[N_];  // 64 KB
  __shared__ float s_minv[4];
  __shared__ int s_mini[4];
  __shared__ int s_win;
  const int t = threadIdx.x;
  const float qx = new_xyz[q * 3 + 0];
  const float qy = new_xyz[q * 3 + 1];
  const float qz = new_xyz[q * 3 + 2];
  const float* X = xyz + (size_t)b * N_ * 3;
  float lmin = 1e30f;
  int lidx = -1;
  for (int j = 0; j < N_ / 256; ++j) {
    int i = t + j * 256;
    float dx = X[i * 3 + 0] - qx;
    float dy = X[i * 3 + 1] - qy;
    float dz = X[i * 3 + 2] - qz;
    float dsq = fmaf(dx, dx, fmaf(dy, dy, dz * dz));
    sd[i] = dsq;
    if (dsq < lmin) { lmin = dsq; lidx = i; }
  }
  __syncthreads();
  for (int r = 0; r < K_; ++r) {
    float v = lmin;
    int ii = lidx;
#pragma unroll
    for (int off = 32; off > 0; off >>= 1) {
      float ov = __shfl_down(v, off);
      int oi = __shfl_down(ii, off);
      if (ov < v) { v = ov; ii = oi; }
    }
    if ((t & 63) == 0) { s_minv[t >> 6] = v; s_mini[t >> 6] = ii; }
    __syncthreads();
    if (t == 0) {
      float bv = s_minv[0]; int bi = s_mini[0];
#pragma unroll
      for (int w = 1; w < 4; ++w)
        if (s_minv[w] < bv) { bv = s_minv[w]; bi = s_mini[w]; }
      knn_idx[q * K_ + r] = bi;
      s_win = bi;
    }
    __syncthreads();
    int wi = s_win;
    if (wi == lidx) {  // unique owner (disjoint index ranges per thread)
      sd[wi] = 1e30f;
      lmin = 1e30f; lidx = -1;
      for (int j = 0; j < N_ / 256; ++j) {
        int i = t + j * 256;
        float dv = sd[i];
        if (dv < lmin) { lmin = dv; lidx = i; }
      }
    }
  }
}

// ---------------------------------------------------------------------------
// Transpose weights into ws (coalesced per-channel access later) and zero the
// stats region (exactly 49152 elements == transpose work, handled same grid).
// ---------------------------------------------------------------------------
__global__ __launch_bounds__(256) void prep_kernel(const float* __restrict__ W1,
                                                   const float* __restrict__ W2,
                                                   float* __restrict__ W1t,
                                                   float* __restrict__ W2t,
                                                   float* __restrict__ stats) {
  int e = blockIdx.x * 256 + threadIdx.x;  // 0 .. 49151
  stats[e] = 0.0f;
  if (e < C1_ * C0_) {
    int co = e / C0_, c = e % C0_;
    W1t[c * C1_ + co] = W1[e];
  } else {
    int e2 = e - C1_ * C0_;
    int co = e2 / C1_, c = e2 % C1_;
    W2t[c * C2_ + co] = W2[e2];
  }
}

// ---------------------------------------------------------------------------
// conv1 stats: gather + conv1 (y1 pre-BN), accumulate per-channel sum/sumsq.
// Grid 1024 blocks x 8 queries each; slot-sliced atomics (64 slots).
// ---------------------------------------------------------------------------
__global__ __launch_bounds__(256) void conv1_stats_kernel(
    const float* __restrict__ xyz, const float* __restrict__ feat,
    const float* __restrict__ new_xyz, const int* __restrict__ knn,
    const float* __restrict__ W1t, const float* __restrict__ b1,
    float* __restrict__ stats1) {
  __shared__ __align__(16) float sinT[C0_][K_];  // transposed: [c][k]
  __shared__ int sidx[K_];
  __shared__ float sred[256];
  const int t = threadIdx.x;
  float psum = 0.f, psumsq = 0.f;
  const int QPB = (B_ * S_) / 1024;  // 8
  for (int qq = 0; qq < QPB; ++qq) {
    const int q = blockIdx.x * QPB + qq;
    const int b = q / S_;
    if (t < K_) sidx[t] = knn[q * K_ + t];
    __syncthreads();
    const float nx = new_xyz[q * 3 + 0];
    const float ny = new_xyz[q * 3 + 1];
    const float nz = new_xyz[q * 3 + 2];
    for (int e = t; e < K_ * C0_; e += 256) {
      int c = e >> 4, kk = e & 15;
      int i = sidx[kk];
      float v;
      if (c < 3)
        v = xyz[((size_t)b * N_ + i) * 3 + c] - (c == 0 ? nx : (c == 1 ? ny : nz));
      else
        v = feat[((size_t)b * N_ + i) * D_ + (c - 3)];
      sinT[c][kk] = v;
    }
    __syncthreads();
    const int co = t & 127, kh = t >> 7;
    float acc[8];
    float bias = b1[co];
#pragma unroll
    for (int k = 0; k < 8; ++k) acc[k] = bias;
    for (int c = 0; c < C0_; ++c) {
      float w = W1t[c * C1_ + co];
      float4 xa = *(const float4*)&sinT[c][kh * 8];
      float4 xb = *(const float4*)&sinT[c][kh * 8 + 4];
      acc[0] = fmaf(w, xa.x, acc[0]);
      acc[1] = fmaf(w, xa.y, acc[1]);
      acc[2] = fmaf(w, xa.z, acc[2]);
      acc[3] = fmaf(w, xa.w, acc[3]);
      acc[4] = fmaf(w, xb.x, acc[4]);
      acc[5] = fmaf(w, xb.y, acc[5]);
      acc[6] = fmaf(w, xb.z, acc[6]);
      acc[7] = fmaf(w, xb.w, acc[7]);
    }
#pragma unroll
    for (int k = 0; k < 8; ++k) {
      psum += acc[k];
      psumsq = fmaf(acc[k], acc[k], psumsq);
    }
    __syncthreads();
  }
  sred[t] = psum;
  __syncthreads();
  float totsum = (t < 128) ? (sred[t] + sred[t + 128]) : 0.f;
  __syncthreads();
  sred[t] = psumsq;
  __syncthreads();
  if (t < 128) {
    float totsq = sred[t] + sred[t + 128];
    float* st = stats1 + (size_t)(blockIdx.x & (NSLOT - 1)) * (2 * C1_);
    atomicAdd(&st[t], totsum);
    atomicAdd(&st[C1_ + t], totsq);
  }
}

__global__ void finalize1_kernel(const float* __restrict__ stats1,
                                 const float* __restrict__ gamma1,
                                 const float* __restrict__ beta1,
                                 float* __restrict__ ss1) {
  int t = threadIdx.x;  // 128
  float s = 0.f, sq = 0.f;
  for (int w = 0; w < NSLOT; ++w) {
    s += stats1[w * 2 * C1_ + t];
    sq += stats1[w * 2 * C1_ + C1_ + t];
  }
  const float M = (float)(B_ * S_ * K_);
  float m = s / M;
  float v = fmaxf(sq / M - m * m, 0.f);
  float sc = gamma1[t] * rsqrtf(v + 1e-5f);
  ss1[t] = sc;
  ss1[C1_ + t] = fmaf(-m, sc, beta1[t]);
}

// ---------------------------------------------------------------------------
// conv2: re-gather, recompute conv1, apply bn1+relu -> LDS, conv2, per-(q,co2)
// max/min over k, accumulate y2 stats. Grid 1024 x 8 queries.
// ---------------------------------------------------------------------------
__global__ __launch_bounds__(256) void conv2_kernel(
    const float* __restrict__ xyz, const float* __restrict__ feat,
    const float* __restrict__ new_xyz, const int* __restrict__ knn,
    const float* __restrict__ W1t, const float* __restrict__ b1,
    const float* __restrict__ ss1, const float* __restrict__ W2t,
    const float* __restrict__ b2, float* __restrict__ maxv,
    float* __restrict__ minv, float* __restrict__ stats2) {
  __shared__ __align__(16) float sinT[C0_][K_];
  __shared__ __align__(16) float sh1T[C1_][20];  // pad 16->20 (bank spread, 16B-aligned rows)
  __shared__ int sidx[K_];
  const int t = threadIdx.x;
  float psum = 0.f, psumsq = 0.f;
  const int QPB = (B_ * S_) / 1024;  // 8
  for (int qq = 0; qq < QPB; ++qq) {
    const int q = blockIdx.x * QPB + qq;
    const int b = q / S_;
    if (t < K_) sidx[t] = knn[q * K_ + t];
    __syncthreads();
    const float nx = new_xyz[q * 3 + 0];
    const float ny = new_xyz[q * 3 + 1];
    const float nz = new_xyz[q * 3 + 2];
    for (int e = t; e < K_ * C0_; e += 256) {
      int c = e >> 4, kk = e & 15;
      int i = sidx[kk];
      float v;
      if (c < 3)
        v = xyz[((size_t)b * N_ + i) * 3 + c] - (c == 0 ? nx : (c == 1 ? ny : nz));
      else
        v = feat[((size_t)b * N_ + i) * D_ + (c - 3)];
      sinT[c][kk] = v;
    }
    __syncthreads();
    {  // conv1 + bn1 + relu -> sh1T[c_in2][k]
      const int co = t & 127, kh = t >> 7;
      float acc[8];
      float bias = b1[co];
#pragma unroll
      for (int k = 0; k < 8; ++k) acc[k] = bias;
      for (int c = 0; c < C0_; ++c) {
        float w = W1t[c * C1_ + co];
        float4 xa = *(const float4*)&sinT[c][kh * 8];
        float4 xb = *(const float4*)&sinT[c][kh * 8 + 4];
        acc[0] = fmaf(w, xa.x, acc[0]);
        acc[1] = fmaf(w, xa.y, acc[1]);
        acc[2] = fmaf(w, xa.z, acc[2]);
        acc[3] = fmaf(w, xa.w, acc[3]);
        acc[4] = fmaf(w, xb.x, acc[4]);
        acc[5] = fmaf(w, xb.y, acc[5]);
        acc[6] = fmaf(w, xb.z, acc[6]);
        acc[7] = fmaf(w, xb.w, acc[7]);
      }
      float sc = ss1[co], sh = ss1[C1_ + co];
#pragma unroll
      for (int k = 0; k < 8; ++k) {
        float h = fmaxf(fmaf(acc[k], sc, sh), 0.f);
        sh1T[co][kh * 8 + k] = h;
      }
    }
    __syncthreads();
    {  // conv2: thread t -> co2 = t
      float acc2[16];
      float bias2 = b2[t];
#pragma unroll
      for (int k = 0; k < 16; ++k) acc2[k] = bias2;
      for (int c = 0; c < C1_; ++c) {
        float w = W2t[c * C2_ + t];
        float4 h0 = *(const float4*)&sh1T[c][0];
        float4 h1 = *(const float4*)&sh1T[c][4];
        float4 h2 = *(const float4*)&sh1T[c][8];
        float4 h3 = *(const float4*)&sh1T[c][12];
        acc2[0] = fmaf(w, h0.x, acc2[0]);
        acc2[1] = fmaf(w, h0.y, acc2[1]);
        acc2[2] = fmaf(w, h0.z, acc2[2]);
        acc2[3] = fmaf(w, h0.w, acc2[3]);
        acc2[4] = fmaf(w, h1.x, acc2[4]);
        acc2[5] = fmaf(w, h1.y, acc2[5]);
        acc2[6] = fmaf(w, h1.z, acc2[6]);
        acc2[7] = fmaf(w, h1.w, acc2[7]);
        acc2[8] = fmaf(w, h2.x, acc2[8]);
        acc2[9] = fmaf(w, h2.y, acc2[9]);
        acc2[10] = fmaf(w, h2.z, acc2[10]);
        acc2[11] = fmaf(w, h2.w, acc2[11]);
        acc2[12] = fmaf(w, h3.x, acc2[12]);
        acc2[13] = fmaf(w, h3.y, acc2[13]);
        acc2[14] = fmaf(w, h3.z, acc2[14]);
        acc2[15] = fmaf(w, h3.w, acc2[15]);
      }
      float mx = acc2[0], mn = acc2[0];
#pragma unroll
      for (int k = 0; k < 16; ++k) {
        psum += acc2[k];
        psumsq = fmaf(acc2[k], acc2[k], psumsq);
        mx = fmaxf(mx, acc2[k]);
        mn = fminf(mn, acc2[k]);
      }
      maxv[(size_t)q * C2_ + t] = mx;
      minv[(size_t)q * C2_ + t] = mn;
    }
    __syncthreads();
  }
  float* st = stats2 + (size_t)(blockIdx.x & (NSLOT - 1)) * (2 * C2_);
  atomicAdd(&st[t], psum);
  atomicAdd(&st[C2_ + t], psumsq);
}

__global__ void finalize2_kernel(const float* __restrict__ stats2,
                                 const float* __restrict__ gamma2,
                                 const float* __restrict__ beta2,
                                 float* __restrict__ ss2) {
  int t = threadIdx.x;  // 256
  float s = 0.f, sq = 0.f;
  for (int w = 0; w < NSLOT; ++w) {
    s += stats2[w * 2 * C2_ + t];
    sq += stats2[w * 2 * C2_ + C2_ + t];
  }
  const float M = (float)(B_ * S_ * K_);
  float m = s / M;
  float v = fmaxf(sq / M - m * m, 0.f);
  float sc = gamma2[t] * rsqrtf(v + 1e-5f);
  ss2[t] = sc;
  ss2[C2_ + t] = fmaf(-m, sc, beta2[t]);
}

// max_k relu(bn(y)) == relu(bn(max_k y)) for scale>=0 (min_k for scale<0)
__global__ __launch_bounds__(256) void out_kernel(const float* __restrict__ maxv,
                                                  const float* __restrict__ minv,
                                                  const float* __restrict__ ss2,
                                                  float* __restrict__ out2) {
  int e = blockIdx.x * 256 + threadIdx.x;
  int co = e & (C2_ - 1);
  float sc = ss2[co], sh = ss2[C2_ + co];
  float v = (sc >= 0.f) ? maxv[e] : minv[e];
  out2[e] = fmaxf(fmaf(v, sc, sh), 0.f);
}

extern "C" void kernel_launch(void* const* d_in, const int* in_sizes, int n_in,
                              void* d_out, int out_size, void* d_ws, size_t ws_size,
                              hipStream_t stream) {
  (void)in_sizes; (void)n_in; (void)out_size; (void)ws_size;
  const float* xyz = (const float*)d_in[0];
  const float* feat = (const float*)d_in[1];
  const float* W1 = (const float*)d_in[2];
  const float* b1 = (const float*)d_in[3];
  const float* gamma1 = (const float*)d_in[4];
  const float* beta1 = (const float*)d_in[5];
  const float* W2 = (const float*)d_in[6];
  const float* b2 = (const float*)d_in[7];
  const float* gamma2 = (const float*)d_in[8];
  const float* beta2 = (const float*)d_in[9];

  float* out = (float*)d_out;
  float* new_xyz = out;                 // [B,S,3]
  float* out2 = out + B_ * S_ * 3;      // [B,S,C2]

  float* ws = (float*)d_ws;
  float* stats1 = ws;                              // 64*256
  float* stats2 = stats1 + NSLOT * 2 * C1_;        // 64*512
  float* ss1 = stats2 + NSLOT * 2 * C2_;           // 256
  float* ss2 = ss1 + 2 * C1_;                      // 512
  float* W1t = ss2 + 2 * C2_;                      // 16384
  float* W2t = W1t + C1_ * C0_;                    // 32768
  int* knn = (int*)(W2t + (size_t)C2_ * C1_);      // B*S*K ints
  float* maxv = (float*)(knn + B_ * S_ * K_);      // B*S*C2
  float* minv = maxv + (size_t)B_ * S_ * C2_;      // B*S*C2

  prep_kernel<<<192, 256, 0, stream>>>(W1, W2, W1t, W2t, stats1);
  fps_kernel<<<B_, 1024, 0, stream>>>(xyz, new_xyz);
  knn_kernel<<<B_ * S_, 256, 0, stream>>>(xyz, new_xyz, knn);
  conv1_stats_kernel<<<1024, 256, 0, stream>>>(xyz, feat, new_xyz, knn, W1t, b1, stats1);
  finalize1_kernel<<<1, 128, 0, stream>>>(stats1, gamma1, beta1, ss1);
  conv2_kernel<<<1024, 256, 0, stream>>>(xyz, feat, new_xyz, knn, W1t, b1, ss1,
                                         W2t, b2, maxv, minv, stats2);
  finalize2_kernel<<<1, 256, 0, stream>>>(stats2, gamma2, beta2, ss2);
  out_kernel<<<(B_ * S_ * C2_) / 256, 256, 0, stream>>>(maxv, minv, ss2, out2);
}